// Round 4
// baseline (671.741 us; speedup 1.0000x reference)
//
#include <hip/hip_runtime.h>
#include <hip/hip_cooperative_groups.h>

namespace cg = cooperative_groups;

#define N1c 25000
#define N2c 5000
#define Dc 256
#define DOUTc 128
#define EPSc 1e-5f
#define NEGc 0.01f
#define NTOT (N1c + N2c)          // concatenated counter space
#define GBLK 256                  // cooperative grid: 1 block/CU
#define BTHR 256

typedef __attribute__((ext_vector_type(8))) short short8;
typedef __attribute__((ext_vector_type(4))) float f32x4;

__device__ __forceinline__ ushort f2bf(float f) {
    unsigned u = __float_as_uint(f);
    u += 0x7fffu + ((u >> 16) & 1u);          // round-to-nearest-even
    return (ushort)(u >> 16);
}
__device__ __forceinline__ float bf2f(ushort u) {
    return __uint_as_float(((unsigned)u) << 16);
}

// ============ cooperative mega-kernel: prep + CSR + gather0 ==================
// Phases (grid.sync between):
//  P0a zero counts, prep Bt1/Bt2, mask_out -> d_out tail
//  P0b conv x[:N1]->bf16, count0/count1 (atomics into concat counts[30000])
//  P1  per-block inclusive scan (CH=1, 65536 threads cover 30000)
//  P2  block 0: exclusive scan of 256 block partials
//  P3  offsets[i] = exclusive prefix (offsets-as-cursor convention)
//  P4  fill unified eidx via atomicAdd(&offsets[d],1)  (post: offsets inclusive)
//  P5  gather0: wave per dst row -> agg0 bf16
__global__ __launch_bounds__(BTHR) void coopA(
    const float* __restrict__ x,
    const int* __restrict__ src0, const int* __restrict__ dst0, const int* __restrict__ val0,
    const int* __restrict__ src1, const int* __restrict__ dst1, const int* __restrict__ val1,
    const int* __restrict__ ts, const int* __restrict__ time_p, const int* __restrict__ itv_p,
    const float* __restrict__ W1l, const float* __restrict__ W1r,
    const float* __restrict__ W2l, const float* __restrict__ W2r,
    int E0, int E1,
    ushort* __restrict__ xb, ushort* __restrict__ Bt1, ushort* __restrict__ Bt2,
    int* __restrict__ counts, int* __restrict__ offsets,
    int* __restrict__ partial, int* __restrict__ bpref,
    int* __restrict__ eidx, ushort* __restrict__ agg0,
    float* __restrict__ mask_out) {
    cg::grid_group grid = cg::this_grid();
    __shared__ int linc[BTHR];
    __shared__ int pbuf[BTHR];
    const int tid = threadIdx.x;
    const int flat = blockIdx.x * BTHR + tid;
    const int NT = GBLK * BTHR;   // 65536
    const int t0 = *time_p, iv = *itv_p;

    // ---- P0a ----
    for (int i = flat; i < NTOT; i += NT) counts[i] = 0;
    for (int i = flat; i < 256 * 512; i += NT) {   // Bt1 [n][512]
        int n = i >> 9, k = i & 511;
        float v = (k < 256) ? W1l[(size_t)k * 256 + n] : W1r[(size_t)(k - 256) * 256 + n];
        Bt1[i] = f2bf(v);
    }
    for (int i = flat; i < 128 * 512; i += NT) {   // Bt2 [n][512]
        int n = i >> 9, k = i & 511;
        float v = (k < 256) ? W2l[(size_t)k * 128 + n] : W2r[(size_t)(k - 256) * 128 + n];
        Bt2[i] = f2bf(v);
    }
    for (int e = flat; e < E1; e += NT) {          // mask1 -> out tail
        int t = ts[val1[e]];
        mask_out[e] = (t >= t0 && t < t0 + iv) ? 1.0f : 0.0f;
    }
    __threadfence();
    grid.sync();

    // ---- P0b ----
    for (int i = flat; i < N1c * 64; i += NT) {    // conv x[:N1] -> bf16
        float4 v = ((const float4*)x)[i];
        ushort4 o;
        o.x = f2bf(v.x); o.y = f2bf(v.y); o.z = f2bf(v.z); o.w = f2bf(v.w);
        ((ushort4*)xb)[i] = o;
    }
    for (int e = flat; e < E0; e += NT) {
        int t = ts[val0[e]];
        if (t >= t0 && t < t0 + iv) atomicAdd(&counts[dst0[e]], 1);
    }
    for (int e = flat; e < E1; e += NT) {
        int t = ts[val1[e]];
        if (t >= t0 && t < t0 + iv) atomicAdd(&counts[N1c + dst1[e]], 1);
    }
    __threadfence();
    grid.sync();

    // ---- P1: per-block inclusive scan of counts chunk ----
    int c = (flat < NTOT) ? counts[flat] : 0;
    linc[tid] = c;
    __syncthreads();
    for (int off = 1; off < BTHR; off <<= 1) {
        int v = (tid >= off) ? linc[tid - off] : 0;
        __syncthreads();
        linc[tid] += v;
        __syncthreads();
    }
    if (tid == BTHR - 1) partial[blockIdx.x] = linc[tid];
    __threadfence();
    grid.sync();

    // ---- P2: block 0 scans the 256 partials (exclusive) ----
    if (blockIdx.x == 0) {
        int pv = partial[tid];
        pbuf[tid] = pv;
        __syncthreads();
        for (int off = 1; off < BTHR; off <<= 1) {
            int v = (tid >= off) ? pbuf[tid - off] : 0;
            __syncthreads();
            pbuf[tid] += v;
            __syncthreads();
        }
        bpref[tid] = pbuf[tid] - pv;               // exclusive block prefix
    }
    __threadfence();
    grid.sync();

    // ---- P3: write exclusive offsets ----
    if (flat < NTOT) offsets[flat] = bpref[blockIdx.x] + linc[tid] - c;
    __threadfence();
    grid.sync();

    // ---- P4: fill unified eidx (offsets become inclusive) ----
    for (int e = flat; e < E0; e += NT) {
        int t = ts[val0[e]];
        if (t >= t0 && t < t0 + iv) {
            int pos = atomicAdd(&offsets[dst0[e]], 1);
            eidx[pos] = src0[e];
        }
    }
    for (int e = flat; e < E1; e += NT) {
        int t = ts[val1[e]];
        if (t >= t0 && t < t0 + iv) {
            int pos = atomicAdd(&offsets[N1c + dst1[e]], 1);
            eidx[pos] = src1[e];
        }
    }
    __threadfence();
    grid.sync();

    // ---- P5: gather0 (wave per row, fp32 x -> bf16 agg0) ----
    int wave = flat >> 6, lane = flat & 63;
    int nwaves = NT >> 6;                          // 1024
    for (int row = wave; row < N1c; row += nwaves) {
        int s1 = offsets[row];
        int s0 = row ? offsets[row - 1] : 0;
        float4 acc = make_float4(0.f, 0.f, 0.f, 0.f);
        for (int j = s0; j < s1; ++j) {
            int s = eidx[j];
            float4 v = *(const float4*)(x + (size_t)s * Dc + lane * 4);
            acc.x += v.x; acc.y += v.y; acc.z += v.z; acc.w += v.w;
        }
        float inv = 1.0f / fmaxf((float)(s1 - s0), 1.0f);
        ushort4 o;
        o.x = f2bf(acc.x * inv); o.y = f2bf(acc.y * inv);
        o.z = f2bf(acc.z * inv); o.w = f2bf(acc.w * inv);
        *(ushort4*)(agg0 + (size_t)row * Dc + lane * 4) = o;
    }
}

// ---------------- gather + mean (bf16 h -> bf16 agg1), layer-1 rows ---------
__global__ void gather_bf16(const ushort* __restrict__ H,
                            const int* __restrict__ offsets,
                            const int* __restrict__ eidx,
                            ushort* __restrict__ agg, int n) {
    int wave = (blockIdx.x * blockDim.x + threadIdx.x) >> 6;
    int lane = threadIdx.x & 63;
    if (wave >= n) return;
    int s1 = offsets[N1c + wave];
    int s0 = offsets[N1c + wave - 1];              // wave=0 -> offsets[N1c-1] = layer0 total
    float4 acc = make_float4(0.f, 0.f, 0.f, 0.f);
    for (int j = s0; j < s1; ++j) {
        int s = eidx[j];
        ushort4 v = *(const ushort4*)(H + (size_t)s * Dc + lane * 4);
        acc.x += bf2f(v.x); acc.y += bf2f(v.y);
        acc.z += bf2f(v.z); acc.w += bf2f(v.w);
    }
    float inv = 1.0f / fmaxf((float)(s1 - s0), 1.0f);
    ushort4 o;
    o.x = f2bf(acc.x * inv); o.y = f2bf(acc.y * inv);
    o.z = f2bf(acc.z * inv); o.w = f2bf(acc.w * inv);
    *(ushort4*)(agg + (size_t)wave * Dc + lane * 4) = o;
}

// ---------------- bf16 MFMA GEMM: C = [Alo|Ahi] @ Bt^T + bias [,BN+leaky] ---
// (unchanged from round 3 — verified) A halves [M][256] bf16, Bt [N][512].
template <int VARIANT>
__global__ __launch_bounds__(128) void gemm_mfma(
    const ushort* __restrict__ Alo, const ushort* __restrict__ Ahi,
    const ushort* __restrict__ Bt,
    const float* __restrict__ bias,
    const float* __restrict__ g, const float* __restrict__ bt,
    const float* __restrict__ rm, const float* __restrict__ rv,
    void* __restrict__ Cout, int M) {
    __shared__ ushort As[64][40];
    __shared__ ushort Bs[128][40];
    int tid = threadIdx.x;
    int wave = tid >> 6, lane = tid & 63;
    int quad = lane >> 4, l16 = lane & 15;
    int m0 = blockIdx.y * 64, n0 = blockIdx.x * 128;
    f32x4 acc[2][8] = {};
    int ar = tid >> 1;
    int ak = (tid & 1) * 16;
    int bn = tid;
    for (int k0 = 0; k0 < 512; k0 += 32) {
        const ushort* Ag = (k0 < 256)
            ? (Alo + (size_t)(m0 + ar) * Dc + k0 + ak)
            : (Ahi + (size_t)(m0 + ar) * Dc + (k0 - 256) + ak);
        uint4 a0 = make_uint4(0, 0, 0, 0), a1 = make_uint4(0, 0, 0, 0);
        if (m0 + ar < M) {
            a0 = *(const uint4*)Ag;
            a1 = *(const uint4*)(Ag + 8);
        }
        const ushort* Bg = Bt + (size_t)(n0 + bn) * 512 + k0;
        uint4 b0 = *(const uint4*)(Bg + 0);
        uint4 b1 = *(const uint4*)(Bg + 8);
        uint4 b2 = *(const uint4*)(Bg + 16);
        uint4 b3 = *(const uint4*)(Bg + 24);
        __syncthreads();
        *(uint4*)&As[ar][ak] = a0;
        *(uint4*)&As[ar][ak + 8] = a1;
        *(uint4*)&Bs[bn][0] = b0;
        *(uint4*)&Bs[bn][8] = b1;
        *(uint4*)&Bs[bn][16] = b2;
        *(uint4*)&Bs[bn][24] = b3;
        __syncthreads();
        short8 af0 = *(const short8*)&As[wave * 32 + l16][quad * 8];
        short8 af1 = *(const short8*)&As[wave * 32 + 16 + l16][quad * 8];
#pragma unroll
        for (int j = 0; j < 8; ++j) {
            short8 bf = *(const short8*)&Bs[j * 16 + l16][quad * 8];
            acc[0][j] = __builtin_amdgcn_mfma_f32_16x16x32_bf16(af0, bf, acc[0][j], 0, 0, 0);
            acc[1][j] = __builtin_amdgcn_mfma_f32_16x16x32_bf16(af1, bf, acc[1][j], 0, 0, 0);
        }
    }
#pragma unroll
    for (int grp = 0; grp < 2; ++grp) {
#pragma unroll
        for (int j = 0; j < 8; ++j) {
            int gn = n0 + j * 16 + l16;
            float sc = 1.f, sh = bias[gn];
            if (VARIANT == 0) {
                float s = g[gn] * rsqrtf(rv[gn] + EPSc);
                sh = (bias[gn] - rm[gn]) * s + bt[gn];
                sc = s;
            }
            int gmb = m0 + wave * 32 + grp * 16 + quad * 4;
#pragma unroll
            for (int r = 0; r < 4; ++r) {
                int gm = gmb + r;
                if (gm >= M) continue;
                float v = acc[grp][j][r];
                if (VARIANT == 0) {
                    v = v * sc + sh;
                    v = v >= 0.f ? v : NEGc * v;
                    ((ushort*)Cout)[(size_t)gm * Dc + gn] = f2bf(v);
                } else {
                    ((float*)Cout)[(size_t)gm * DOUTc + gn] = v + sh;
                }
            }
        }
    }
}

extern "C" void kernel_launch(void* const* d_in, const int* in_sizes, int n_in,
                              void* d_out, int out_size, void* d_ws, size_t ws_size,
                              hipStream_t stream) {
    const float* x    = (const float*)d_in[0];
    const int* src0   = (const int*)d_in[1];
    const int* dst0   = (const int*)d_in[2];
    const int* val0   = (const int*)d_in[3];
    const int* src1   = (const int*)d_in[4];
    const int* dst1   = (const int*)d_in[5];
    const int* val1   = (const int*)d_in[6];
    const int* ts     = (const int*)d_in[7];
    const int* time_p = (const int*)d_in[8];
    const int* itv_p  = (const int*)d_in[9];
    const float* W1l  = (const float*)d_in[10];
    const float* W1r  = (const float*)d_in[11];
    const float* b1   = (const float*)d_in[12];
    const float* g1   = (const float*)d_in[13];
    const float* bt1  = (const float*)d_in[14];
    const float* rm1  = (const float*)d_in[15];
    const float* rv1  = (const float*)d_in[16];
    const float* W2l  = (const float*)d_in[17];
    const float* W2r  = (const float*)d_in[18];
    const float* b2   = (const float*)d_in[19];
    int E0 = in_sizes[1];
    int E1 = in_sizes[4];
    float* out = (float*)d_out;

    // ---- workspace layout ----
    ushort* agg0 = (ushort*)d_ws;                  // [N1][256]
    ushort* xb   = agg0 + (size_t)N1c * Dc;        // [N1][256]
    ushort* h    = xb   + (size_t)N1c * Dc;        // [N1][256]
    ushort* agg1 = h    + (size_t)N1c * Dc;        // [N2][256]
    ushort* Bt1  = agg1 + (size_t)N2c * Dc;        // [256][512]
    ushort* Bt2  = Bt1  + 256 * 512;               // [128][512]
    int* ip      = (int*)(Bt2 + 128 * 512);
    int* counts   = ip;            ip += NTOT;
    int* offsets  = ip;            ip += NTOT;
    int* partial  = ip;            ip += GBLK;
    int* bpref    = ip;            ip += GBLK;
    int* eidx     = ip;            ip += E0 + E1;
    float* mask_tail = out + (size_t)N2c * DOUTc;

    void* args[] = {
        (void*)&x, (void*)&src0, (void*)&dst0, (void*)&val0,
        (void*)&src1, (void*)&dst1, (void*)&val1,
        (void*)&ts, (void*)&time_p, (void*)&itv_p,
        (void*)&W1l, (void*)&W1r, (void*)&W2l, (void*)&W2r,
        (void*)&E0, (void*)&E1,
        (void*)&xb, (void*)&Bt1, (void*)&Bt2,
        (void*)&counts, (void*)&offsets, (void*)&partial, (void*)&bpref,
        (void*)&eidx, (void*)&agg0, (void*)&mask_tail,
    };
    hipLaunchCooperativeKernel((const void*)coopA, dim3(GBLK), dim3(BTHR),
                               args, 0, stream);

    gemm_mfma<0><<<dim3(2, (N1c + 63) / 64), 128, 0, stream>>>(
        agg0, xb, Bt1, b1, g1, bt1, rm1, rv1, h, N1c);
    gather_bf16<<<(N2c + 3) / 4, 256, 0, stream>>>(h, offsets, eidx, agg1, N2c);
    gemm_mfma<1><<<dim3(1, (N2c + 63) / 64), 128, 0, stream>>>(
        agg1, h, Bt2, b2, nullptr, nullptr, nullptr, nullptr, out, N2c);
}